// Round 4
// baseline (8973.173 us; speedup 1.0000x reference)
//
#include <hip/hip_runtime.h>
#include <stdint.h>

#define NN 50000
#define NE 800000
#define DD 512
#define EPSF 1e-5f
#define STATE_BYTES ((size_t)NN*DD*2)          // 51,200,000

typedef __attribute__((ext_vector_type(8))) short short8;
typedef __attribute__((ext_vector_type(8))) unsigned short u16x8;
typedef __attribute__((ext_vector_type(4))) float floatx4;

__device__ __forceinline__ unsigned short f2b(float f){
  unsigned int u = __float_as_uint(f);
  u += 0x7fffu + ((u >> 16) & 1u);   // RNE
  return (unsigned short)(u >> 16);
}
__device__ __forceinline__ float b2f(unsigned short b){
  return __uint_as_float(((unsigned int)b) << 16);
}

// async global->LDS, 16B per lane; LDS dest = wave-uniform base + lane*16
__device__ __forceinline__ void gl_lds16(const unsigned short* g, unsigned short* l){
  __builtin_amdgcn_global_load_lds(
      (const __attribute__((address_space(1))) unsigned int*)(uintptr_t)g,
      (__attribute__((address_space(3))) unsigned int*)(uintptr_t)l,
      16, 0, 0);
}

// ---------------- diagnostic probe (fires only if ws too small) ----------------
__global__ void probe_k(float* __restrict__ out, float val, int n){
  int i = blockIdx.x*256 + threadIdx.x;
  if (i < n) out[i] = val;
}

// ---------------- CSR build ----------------
__global__ void count_k(const int* __restrict__ dst, int* __restrict__ cnt){
  int i = blockIdx.x*256 + threadIdx.x;
  if (i < NE) atomicAdd(&cnt[dst[i]], 1);
}

__global__ void scan_k(const int* __restrict__ cnt, int* __restrict__ offs,
                       int* __restrict__ cursor, float* __restrict__ dscale){
  __shared__ int sd[1024];
  __shared__ int run;
  int t = threadIdx.x;
  if (t == 0) run = 0;
  __syncthreads();
  for (int base = 0; base < NN; base += 1024){
    int i = base + t;
    int v = (i < NN) ? cnt[i] : 0;
    sd[t] = v;
    __syncthreads();
    for (int o = 1; o < 1024; o <<= 1){
      int x = (t >= o) ? sd[t-o] : 0;
      __syncthreads();
      sd[t] += x;
      __syncthreads();
    }
    int incl = sd[t];
    int r = run;
    if (i < NN){
      int excl = r + incl - v;
      offs[i] = excl;
      cursor[i] = excl;
      dscale[i] = 1.0f / (float)(v > 0 ? v : 1);
    }
    __syncthreads();
    if (t == 1023) run += incl;
    __syncthreads();
  }
  if (t == 0) offs[NN] = run;
}

__global__ void scatter_k(const int* __restrict__ src, const int* __restrict__ dst,
                          int* __restrict__ cursor, int* __restrict__ esrc){
  int i = blockIdx.x*256 + threadIdx.x;
  if (i < NE){
    int d = dst[i];
    int pos = atomicAdd(&cursor[d], 1);
    esrc[pos] = src[i];
  }
}

// ---------------- h -> bf16 ----------------
__global__ __launch_bounds__(256) void cvt_k(const float* __restrict__ h,
                                             unsigned short* __restrict__ o){
  int idx = blockIdx.x*256 + threadIdx.x;      // NN*64 threads
  if (idx >= NN*64) return;
  const floatx4* hp = (const floatx4*)(h + (size_t)idx*8);
  floatx4 v0 = hp[0], v1 = hp[1];
  u16x8 r;
  #pragma unroll
  for (int t = 0; t < 4; t++){ r[t] = f2b(v0[t]); r[4+t] = f2b(v1[t]); }
  *(u16x8*)(o + (size_t)idx*8) = r;
}

// batched transpose: src [nmat][R][C] f32 -> dst [nmat][C][R] bf16
__global__ void transpose_k(const float* __restrict__ src, unsigned short* __restrict__ dst,
                            int R, int C){
  __shared__ float tile[32][33];
  const float* Sp = src + (size_t)blockIdx.z * R * C;
  unsigned short* Dp = dst + (size_t)blockIdx.z * R * C;
  int c  = blockIdx.x*32 + threadIdx.x;
  int r0 = blockIdx.y*32;
  for (int j = threadIdx.y; j < 32; j += 8)
    tile[j][threadIdx.x] = Sp[(size_t)(r0 + j)*C + c];
  __syncthreads();
  int rr = r0 + threadIdx.x;
  int cc = blockIdx.x*32;
  for (int j = threadIdx.y; j < 32; j += 8)
    Dp[(size_t)(cc + j)*R + rr] = f2b(tile[threadIdx.x][j]);
}

// ---------------- aggregation (one wave per node, 4-edge ILP) ----------------
__global__ __launch_bounds__(256) void agg_k(
    const unsigned short* __restrict__ X,
    const int* __restrict__ offs, const int* __restrict__ esrc,
    unsigned short* __restrict__ S, unsigned short* __restrict__ Mx)
{
  int wave = threadIdx.x >> 6;
  int lane = threadIdx.x & 63;
  int node = blockIdx.x*4 + wave;
  if (node >= NN) return;
  int beg = offs[node], end = offs[node+1];
  float sum[8], mx[8];
  #pragma unroll
  for (int t = 0; t < 8; t++){ sum[t] = 0.f; mx[t] = -3.4e38f; }
  int e = beg;
  for (; e + 4 <= end; e += 4){
    int s0 = esrc[e+0], s1 = esrc[e+1], s2 = esrc[e+2], s3 = esrc[e+3];
    u16x8 v0 = *(const u16x8*)(X + (size_t)s0*DD + lane*8);
    u16x8 v1 = *(const u16x8*)(X + (size_t)s1*DD + lane*8);
    u16x8 v2 = *(const u16x8*)(X + (size_t)s2*DD + lane*8);
    u16x8 v3 = *(const u16x8*)(X + (size_t)s3*DD + lane*8);
    #pragma unroll
    for (int t = 0; t < 8; t++){
      float f0 = b2f(v0[t]), f1 = b2f(v1[t]), f2 = b2f(v2[t]), f3 = b2f(v3[t]);
      sum[t] += (f0 + f1) + (f2 + f3);
      mx[t] = fmaxf(fmaxf(mx[t], fmaxf(f0, f1)), fmaxf(f2, f3));
    }
  }
  for (; e < end; e++){
    int s = esrc[e];
    u16x8 v = *(const u16x8*)(X + (size_t)s*DD + lane*8);
    #pragma unroll
    for (int t = 0; t < 8; t++){
      float f = b2f(v[t]);
      sum[t] += f;
      mx[t] = fmaxf(mx[t], f);
    }
  }
  if (beg == end){
    #pragma unroll
    for (int t = 0; t < 8; t++) mx[t] = 0.f;
  }
  u16x8 sv, mv;
  #pragma unroll
  for (int t = 0; t < 8; t++){ sv[t] = f2b(sum[t]); mv[t] = f2b(mx[t]); }
  *(u16x8*)(S  + (size_t)node*DD + lane*8) = sv;
  *(u16x8*)(Mx + (size_t)node*DD + lane*8) = mv;
}

// ---------------- GEMM (bf16 MFMA 16x16x32, 128x128 tile, BK=64, dbuf) -------
// Round-3 proven base (swizzled BK=64 staging, XCD-bijective 1D grid) plus the
// catalog's MINIMUM 2-PHASE pipeline: double-buffered LDS, STAGE(t+1, nbuf)
// issued BEFORE computing tile t, ONE __syncthreads per iteration. The
// barrier's implicit vmcnt(0)+lgkmcnt(0) drain lands after ~300 cycles of
// ds_read+MFMA, so staging latency is hidden instead of exposed.
// Race-freedom: barrier at end of iter t guarantees (a) all waves' ds_reads of
// buf done (lgkmcnt0) before iter t+1 stages into buf, (b) all gl_lds writes
// to nbuf landed (vmcnt0) before iter t+1 reads them.
// mode 0: kb: 0=P0(X)@W0, 1=P1(S)@W1, 2=P1(S)@W2 *dscale (epi), 3=P2(Max)@W3
// mode 1: A = concat(P0..P3) along K (K=2048), kb=0
// biases skipped: they cancel in the node-axis normalization
__global__ __launch_bounds__(256) void gemm_stats(
    const unsigned short* __restrict__ P0, const unsigned short* __restrict__ P1,
    const unsigned short* __restrict__ P2, const unsigned short* __restrict__ P3,
    const float* __restrict__ dscale,
    const unsigned short* __restrict__ Wslot,  // [4][DD][K] bf16 ([e][k]) slot base
    int K, int mode,
    unsigned short* __restrict__ Z,            // [4][NN][DD] bf16 (slice = kb)
    float* __restrict__ stats)                 // [4][2][512] slot base
{
  __shared__ __align__(16) unsigned short As[2*8192];  // 2 x [128][64] swizzled
  __shared__ __align__(16) unsigned short Bs[2*8192];

  // ---- bijective XCD swizzle (works for any gridDim) ----
  const int nwg = gridDim.x;
  const int q8 = nwg >> 3, r8 = nwg & 7;
  const int xcd = blockIdx.x & 7, idx8 = blockIdx.x >> 3;
  const int swz = (xcd < r8 ? xcd*(q8+1) : r8*(q8+1) + (xcd-r8)*q8) + idx8;
  int mg, y, kb;
  if (!mode){ mg = swz >> 4; y = (swz >> 2) & 3; kb = swz & 3; }
  else      { mg = swz >> 2; y = swz & 3;        kb = 0; }

  const unsigned short* A = P0;
  int scaleEpi = 0;
  if (!mode){
    if      (kb == 1) A = P1;
    else if (kb == 2){ A = P1; scaleEpi = 1; }
    else if (kb == 3) A = P2;
  }
  const unsigned short* W = Wslot + (size_t)(mode ? 0 : kb) * K * DD;

  const int m0 = mg * 128;
  const int n0 = y * 128;
  const int tid = threadIdx.x;
  const int wid = tid >> 6, lane = tid & 63;
  const int waveM = (wid & 1) * 64, waveN = (wid >> 1) * 64;
  const int quad = lane >> 4, l15 = lane & 15;

  // staging map: call c (0..3) covers rows c*32..c*32+31; thread t -> local
  // row lr = c*32 + (t>>3), phys chunk t&7. Global src chunk = (t&7)^(lr&7).
  const int sr = tid >> 3;                         // 0..31
  const int gch = ((tid & 7) ^ (sr & 7)) * 8;      // inverse-swizzled src chunk (elems)
  size_t aRow[4], bRow[4];
  #pragma unroll
  for (int c = 0; c < 4; c++){
    int r = m0 + c*32 + sr; if (r > NN-1) r = NN-1;  // clamp; masked in epilogue
    aRow[c] = (size_t)r * DD + gch;
    bRow[c] = (size_t)(n0 + c*32 + sr) * K + gch;
  }

  // fragment read offsets: row = waveM/N + 16i + l15 (row&7 = l15&7);
  // logical chunk kk*4+quad -> phys ((kk*4+quad)^(l15&7))
  const int rsw = l15 & 7;
  const int ph0 = (quad ^ rsw) * 8;                // kk=0 (elems)
  const int ph1 = ((4 | quad) ^ rsw) * 8;          // kk=1
  const int arow = (waveM + l15) * 64;
  const int brow = (waveN + l15) * 64;

  const int NT = K >> 6;

  auto STAGE = [&](int tt, int buf){
    int kt = tt << 6;
    const unsigned short* Ak = A;
    int acol = kt;
    if (mode){
      int seg = kt >> 9;
      Ak = (seg == 0) ? P0 : (seg == 1) ? P1 : (seg == 2) ? P2 : P3;
      acol = kt & 511;
    }
    #pragma unroll
    for (int c = 0; c < 4; c++){
      gl_lds16(Ak + aRow[c] + acol, As + buf*8192 + c*2048 + tid*8);
      gl_lds16(W + bRow[c] + kt,    Bs + buf*8192 + c*2048 + tid*8);
    }
  };

  floatx4 acc[4][4];
  #pragma unroll
  for (int i = 0; i < 4; i++)
    #pragma unroll
    for (int j = 0; j < 4; j++)
      #pragma unroll
      for (int r = 0; r < 4; r++) acc[i][j][r] = 0.f;

  STAGE(0, 0);
  __syncthreads();                                 // tile 0 landed (vmcnt0 drain)

  for (int t = 0; t < NT; t++){
    const int buf = t & 1;
    if (t + 1 < NT) STAGE(t + 1, buf ^ 1);         // overlap with compute below
    const unsigned short* LAb = As + buf*8192;
    const unsigned short* LBb = Bs + buf*8192;
    short8 a0[4], a1[4], b0[4], b1[4];
    #pragma unroll
    for (int i = 0; i < 4; i++){
      a0[i] = *(const short8*)(LAb + arow + i*1024 + ph0);
      a1[i] = *(const short8*)(LAb + arow + i*1024 + ph1);
      b0[i] = *(const short8*)(LBb + brow + i*1024 + ph0);
      b1[i] = *(const short8*)(LBb + brow + i*1024 + ph1);
    }
    #pragma unroll
    for (int i = 0; i < 4; i++)
      #pragma unroll
      for (int j = 0; j < 4; j++){
        acc[i][j] = __builtin_amdgcn_mfma_f32_16x16x32_bf16(a0[i], b0[j], acc[i][j], 0, 0, 0);
        acc[i][j] = __builtin_amdgcn_mfma_f32_16x16x32_bf16(a1[i], b1[j], acc[i][j], 0, 0, 0);
      }
    __syncthreads();   // drains: reads of buf done; stage into buf^1 landed
  }

  // epilogue: optional row-scale (mean branch), store z bf16, column stats
  float ds[4][4];
  if (scaleEpi){
    #pragma unroll
    for (int i = 0; i < 4; i++){
      int rbase = m0 + waveM + 16*i + quad*4;
      #pragma unroll
      for (int r = 0; r < 4; r++){
        int grow = rbase + r;
        ds[i][r] = dscale[grow < NN ? grow : NN-1];
      }
    }
  }
  #pragma unroll
  for (int j = 0; j < 4; j++){
    float ps = 0.f, pq = 0.f;
    int gcol = n0 + waveN + 16*j + l15;
    #pragma unroll
    for (int i = 0; i < 4; i++){
      int rbase = m0 + waveM + 16*i + quad*4;
      #pragma unroll
      for (int r = 0; r < 4; r++){
        int grow = rbase + r;
        float v = acc[i][j][r];
        if (scaleEpi) v *= ds[i][r];
        bool ok = grow < NN;
        float vm = ok ? v : 0.f;
        ps += vm; pq += vm*vm;
        if (ok) Z[((size_t)kb*NN + grow)*DD + gcol] = f2b(v);
      }
    }
    ps += __shfl_xor(ps, 16); ps += __shfl_xor(ps, 32);
    pq += __shfl_xor(pq, 16); pq += __shfl_xor(pq, 32);
    if (quad == 0){
      atomicAdd(&stats[kb*1024 + gcol], ps);
      atomicAdd(&stats[kb*1024 + 512 + gcol], pq);
    }
  }
}

// ---------------- normalize + relu + weighted combine (4 branches) -----------
__global__ __launch_bounds__(256) void combine_k(
    const unsigned short* __restrict__ Z, const float* __restrict__ stats,
    const float* __restrict__ g, const float* __restrict__ beta,
    const float* __restrict__ w,
    unsigned short* __restrict__ out, int addFlag)
{
  int idx = blockIdx.x*256 + threadIdx.x;
  if (idx >= NN*64) return;
  int node = idx >> 6;
  int e0 = (idx & 63) * 8;
  float acc[8];
  #pragma unroll
  for (int t = 0; t < 8; t++) acc[t] = 0.f;
  const float invn = 1.f / (float)NN;
  #pragma unroll
  for (int k = 0; k < 4; k++){
    float wk = w[k];
    u16x8 zv = *(const u16x8*)(Z + ((size_t)k*NN + node)*DD + e0);
    #pragma unroll
    for (int t = 0; t < 8; t++){
      int e = e0 + t;
      float mu  = stats[k*1024 + e] * invn;
      float var = stats[k*1024 + 512 + e] * invn - mu*mu;
      float inv = rsqrtf(var + EPSF);
      float val = (b2f(zv[t]) - mu) * inv * g[k*DD + e] + beta[k*DD + e];
      acc[t] += wk * fmaxf(val, 0.f);
    }
  }
  unsigned short* op = out + (size_t)node*DD + e0;
  u16x8 res;
  if (addFlag){
    u16x8 prev = *(const u16x8*)op;
    #pragma unroll
    for (int t = 0; t < 8; t++) res[t] = f2b(b2f(prev[t]) + acc[t]);
  } else {
    #pragma unroll
    for (int t = 0; t < 8; t++) res[t] = f2b(acc[t]);
  }
  *(u16x8*)op = res;
}

// ---------------- final BN + relu + residual (reads bf16 h copy) -------------
__global__ __launch_bounds__(256) void bn_k(
    const unsigned short* __restrict__ Z, const float* __restrict__ stats,
    const float* __restrict__ g, const float* __restrict__ b,
    const unsigned short* __restrict__ hb, float* __restrict__ out)
{
  int idx = blockIdx.x*256 + threadIdx.x;
  if (idx >= NN*64) return;
  int node = idx >> 6, e0 = (idx & 63) * 8;
  const float invn = 1.f / (float)NN;
  u16x8 zv = *(const u16x8*)(Z + (size_t)node*DD + e0);
  u16x8 hv = *(const u16x8*)(hb + (size_t)node*DD + e0);
  #pragma unroll
  for (int t = 0; t < 8; t++){
    int e = e0 + t;
    float mu  = stats[e] * invn;
    float var = stats[512 + e] * invn - mu*mu;
    float val = (b2f(zv[t]) - mu) * rsqrtf(var + EPSF) * g[e] + b[e];
    out[(size_t)node*DD + e] = b2f(hv[t]) + fmaxf(val, 0.f);
  }
}

extern "C" void kernel_launch(void* const* d_in, const int* in_sizes, int n_in,
                              void* d_out, int out_size, void* d_ws, size_t ws_size,
                              hipStream_t stream)
{
  const float* h    = (const float*)d_in[0];
  const int*   src  = (const int*)d_in[1];
  const int*   dst  = (const int*)d_in[2];
  const float* wf   = (const float*)d_in[3];
  const float* wm   = (const float*)d_in[4];
  const float* wl   = (const float*)d_in[5];
  const float* pfW  = (const float*)d_in[6];
  const float* pfg  = (const float*)d_in[8];
  const float* pfbt = (const float*)d_in[9];
  const float* pmW  = (const float*)d_in[10];
  const float* pmg  = (const float*)d_in[12];
  const float* pmbt = (const float*)d_in[13];
  const float* plW  = (const float*)d_in[14];
  const float* plg  = (const float*)d_in[16];
  const float* plbt = (const float*)d_in[17];
  const float* catW = (const float*)d_in[18];
  const float* bng  = (const float*)d_in[20];
  const float* bnb  = (const float*)d_in[21];
  float* out = (float*)d_out;
  (void)in_sizes; (void)n_in; (void)out_size;

  // ---- workspace layout (d_ws) ----
  char* ws = (char*)d_ws;
  size_t off = 0;
  auto alloc = [&](size_t bytes)->char*{
    char* p = ws + off;
    off = (off + bytes + 255) & ~(size_t)255;
    return p;
  };
  unsigned short* hb  = (unsigned short*)alloc(STATE_BYTES);   // bf16 h, live to end
  unsigned short* A2  = (unsigned short*)alloc(STATE_BYTES);   // l1
  unsigned short* A3  = (unsigned short*)alloc(STATE_BYTES);   // l2
  int*   esrc   = (int*)alloc((size_t)NE*4);
  int*   cnt    = (int*)alloc((size_t)NN*4);
  int*   cursor = (int*)alloc((size_t)NN*4);
  int*   offs   = (int*)alloc((size_t)(NN+1)*4);
  float* dscale = (float*)alloc((size_t)NN*4);
  float* stats  = (float*)alloc((size_t)11*4096*4);
  unsigned short* Z = (unsigned short*)alloc(4*STATE_BYTES);   // 4 branch slices

  if (off > ws_size){
    probe_k<<<dim3((NN*DD+255)/256), dim3(256), 0, stream>>>(out, (float)ws_size, NN*DD);
    return;
  }

  // ---- buffers hosted outside d_ws ----
  unsigned short* A0 = (unsigned short*)d_out;                         // s1 -> m1
  unsigned short* A1 = (unsigned short*)((char*)d_out + STATE_BYTES);  // s2 -> m2
  unsigned short* Sb = (unsigned short*)h;                             // h dead after cvt
  unsigned short* Mb = (unsigned short*)((char*)h + STATE_BYTES);
  unsigned short* WT_PL  = (unsigned short*)pfW;                       // 10.49 MB in 12.58
  unsigned short* WT_PM  = (unsigned short*)plW;                       // 4.19 MB
  unsigned short* WT_CAT = (unsigned short*)((char*)plW + 4194304);    // 2.10 MB
  unsigned short* WT_PF  = (unsigned short*)((char*)plW + 6291456);    // 6.29 MB (bounced)

  hipMemsetAsync(cnt, 0, (size_t)NN*4, stream);
  hipMemsetAsync(stats, 0, (size_t)11*4096*4, stream);

  // h -> bf16 FIRST (h region becomes scratch afterwards)
  cvt_k<<<dim3(12500), dim3(256), 0, stream>>>(h, hb);

  // CSR
  count_k  <<<dim3((NE+255)/256), dim3(256), 0, stream>>>(dst, cnt);
  scan_k   <<<dim3(1), dim3(1024), 0, stream>>>(cnt, offs, cursor, dscale);
  scatter_k<<<dim3((NE+255)/256), dim3(256), 0, stream>>>(src, dst, cursor, esrc);

  // weight transposes (ordering breaks the src/dst cycle; pf bounces via Z)
  transpose_k<<<dim3(16,16,12), dim3(32,8), 0, stream>>>(pfW, (unsigned short*)Z, 512, 512);
  transpose_k<<<dim3(16,16,20), dim3(32,8), 0, stream>>>(plW, WT_PL, 512, 512);  // kills pfW
  transpose_k<<<dim3(16,16, 8), dim3(32,8), 0, stream>>>(pmW, WT_PM, 512, 512);  // kills plW
  transpose_k<<<dim3(16,64, 1), dim3(32,8), 0, stream>>>(catW, WT_CAT, 2048, 512);
  hipMemcpyAsync(WT_PF, Z, 6291456, hipMemcpyDeviceToDevice, stream);           // Z free now

  dim3 gblock(256);
  dim3 cgrid(12500), cblock(256);

  auto wslot = [&](int slot)->const unsigned short*{
    if (slot < 3)  return WT_PF + (size_t)slot*1048576;
    if (slot < 5)  return WT_PM + (size_t)(slot-3)*1048576;
    return WT_PL + (size_t)(slot-5)*1048576;
  };
  auto agg = [&](const unsigned short* X){
    agg_k<<<dim3(12500), dim3(256), 0, stream>>>(X, offs, esrc, Sb, Mb);
  };
  auto mixed = [&](int slot, const unsigned short* X,
                   const float* wrow, const float* g, const float* beta,
                   unsigned short* o, int add0){
    float* st = stats + (size_t)slot*4096;
    // 1D grid: 391 m-groups x (4 n-blocks x 4 branches) = 6256 blocks
    gemm_stats<<<dim3(391*16), gblock, 0, stream>>>(X, Sb, Mb, Mb, dscale,
        wslot(slot), DD, 0, Z, st);
    combine_k<<<cgrid, cblock, 0, stream>>>(Z, st, g, beta, wrow, o, add0);
  };

  // schedule (slots: 0..2=pf, 3..4=pm, 5..9=pl)
  agg(hb);
  mixed(0, hb, wf,   pfg+0,    pfbt+0,    A0, 0);   // s1
  mixed(1, hb, wf+4, pfg+2048, pfbt+2048, A1, 0);   // s2
  agg(A0);                                          // agg(s1)
  mixed(2, A0, wf+8, pfg+4096, pfbt+4096, A1, 1);   // s2 += f(s1)
  mixed(3, A0, wm,   pmg+0,    pmbt+0,    A0, 0);   // m1 over s1
  agg(A1);                                          // agg(s2)
  mixed(4, A1, wm+4, pmg+2048, pmbt+2048, A1, 0);   // m2 over s2
  agg(A0);                                          // agg(m1)
  mixed(5, A0, wl,    plg+0,    plbt+0,    A2, 0);  // l1
  mixed(7, A0, wl+8,  plg+4096, plbt+4096, A3, 0);  // l2
  agg(A1);                                          // agg(m2)
  mixed(6, A1, wl+4,  plg+2048, plbt+2048, A2, 1);
  mixed(8, A1, wl+12, plg+6144, plbt+6144, A3, 1);
  agg(A2);                                          // agg(l1)
  mixed(9, A2, wl+16, plg+8192, plbt+8192, A3, 1);

  // final: concat(m1,m2,l1,l2) @ cat_W -> BN over nodes -> relu -> + h
  // 1D grid: 391 m-groups x 4 n-blocks = 1564 blocks
  gemm_stats<<<dim3(391*4), gblock, 0, stream>>>(A0, A1, A2, A3, dscale,
      WT_CAT, 4*DD, 1, Z, stats + 10*4096);
  bn_k<<<cgrid, cblock, 0, stream>>>(Z, stats + 10*4096, bng, bnb, hb, out);
}

// Round 5
// 4664.953 us; speedup vs baseline: 1.9235x; 1.9235x over previous
//
#include <hip/hip_runtime.h>
#include <stdint.h>

#define NN 50000
#define NE 800000
#define DD 512
#define EPSF 1e-5f
#define STATE_BYTES ((size_t)NN*DD*2)          // 51,200,000

typedef __attribute__((ext_vector_type(8))) short short8;
typedef __attribute__((ext_vector_type(8))) unsigned short u16x8;
typedef __attribute__((ext_vector_type(4))) float floatx4;
typedef __attribute__((ext_vector_type(16))) float f32x16;

__device__ __forceinline__ unsigned short f2b(float f){
  unsigned int u = __float_as_uint(f);
  u += 0x7fffu + ((u >> 16) & 1u);   // RNE
  return (unsigned short)(u >> 16);
}
__device__ __forceinline__ float b2f(unsigned short b){
  return __uint_as_float(((unsigned int)b) << 16);
}

// async global->LDS, 16B per lane; LDS dest = wave-uniform base + lane*16
__device__ __forceinline__ void gl_lds16(const unsigned short* g, unsigned short* l){
  __builtin_amdgcn_global_load_lds(
      (const __attribute__((address_space(1))) unsigned int*)(uintptr_t)g,
      (__attribute__((address_space(3))) unsigned int*)(uintptr_t)l,
      16, 0, 0);
}

// ---------------- diagnostic probe (fires only if ws too small) ----------------
__global__ void probe_k(float* __restrict__ out, float val, int n){
  int i = blockIdx.x*256 + threadIdx.x;
  if (i < n) out[i] = val;
}

// ---------------- CSR build ----------------
__global__ void count_k(const int* __restrict__ dst, int* __restrict__ cnt){
  int i = blockIdx.x*256 + threadIdx.x;
  if (i < NE) atomicAdd(&cnt[dst[i]], 1);
}

__global__ void scan_k(const int* __restrict__ cnt, int* __restrict__ offs,
                       int* __restrict__ cursor, float* __restrict__ dscale){
  __shared__ int sd[1024];
  __shared__ int run;
  int t = threadIdx.x;
  if (t == 0) run = 0;
  __syncthreads();
  for (int base = 0; base < NN; base += 1024){
    int i = base + t;
    int v = (i < NN) ? cnt[i] : 0;
    sd[t] = v;
    __syncthreads();
    for (int o = 1; o < 1024; o <<= 1){
      int x = (t >= o) ? sd[t-o] : 0;
      __syncthreads();
      sd[t] += x;
      __syncthreads();
    }
    int incl = sd[t];
    int r = run;
    if (i < NN){
      int excl = r + incl - v;
      offs[i] = excl;
      cursor[i] = excl;
      dscale[i] = 1.0f / (float)(v > 0 ? v : 1);
    }
    __syncthreads();
    if (t == 1023) run += incl;
    __syncthreads();
  }
  if (t == 0) offs[NN] = run;
}

__global__ void scatter_k(const int* __restrict__ src, const int* __restrict__ dst,
                          int* __restrict__ cursor, int* __restrict__ esrc){
  int i = blockIdx.x*256 + threadIdx.x;
  if (i < NE){
    int d = dst[i];
    int pos = atomicAdd(&cursor[d], 1);
    esrc[pos] = src[i];
  }
}

// ---------------- h -> bf16 ----------------
__global__ __launch_bounds__(256) void cvt_k(const float* __restrict__ h,
                                             unsigned short* __restrict__ o){
  int idx = blockIdx.x*256 + threadIdx.x;      // NN*64 threads
  if (idx >= NN*64) return;
  const floatx4* hp = (const floatx4*)(h + (size_t)idx*8);
  floatx4 v0 = hp[0], v1 = hp[1];
  u16x8 r;
  #pragma unroll
  for (int t = 0; t < 4; t++){ r[t] = f2b(v0[t]); r[4+t] = f2b(v1[t]); }
  *(u16x8*)(o + (size_t)idx*8) = r;
}

// batched transpose: src [nmat][R][C] f32 -> dst [nmat][C][R] bf16
__global__ void transpose_k(const float* __restrict__ src, unsigned short* __restrict__ dst,
                            int R, int C){
  __shared__ float tile[32][33];
  const float* Sp = src + (size_t)blockIdx.z * R * C;
  unsigned short* Dp = dst + (size_t)blockIdx.z * R * C;
  int c  = blockIdx.x*32 + threadIdx.x;
  int r0 = blockIdx.y*32;
  for (int j = threadIdx.y; j < 32; j += 8)
    tile[j][threadIdx.x] = Sp[(size_t)(r0 + j)*C + c];
  __syncthreads();
  int rr = r0 + threadIdx.x;
  int cc = blockIdx.x*32;
  for (int j = threadIdx.y; j < 32; j += 8)
    Dp[(size_t)(cc + j)*R + rr] = f2b(tile[threadIdx.x][j]);
}

// ---------------- aggregation (one wave per node, 4-edge ILP) ----------------
__global__ __launch_bounds__(256) void agg_k(
    const unsigned short* __restrict__ X,
    const int* __restrict__ offs, const int* __restrict__ esrc,
    unsigned short* __restrict__ S, unsigned short* __restrict__ Mx)
{
  int wave = threadIdx.x >> 6;
  int lane = threadIdx.x & 63;
  int node = blockIdx.x*4 + wave;
  if (node >= NN) return;
  int beg = offs[node], end = offs[node+1];
  float sum[8], mx[8];
  #pragma unroll
  for (int t = 0; t < 8; t++){ sum[t] = 0.f; mx[t] = -3.4e38f; }
  int e = beg;
  for (; e + 4 <= end; e += 4){
    int s0 = esrc[e+0], s1 = esrc[e+1], s2 = esrc[e+2], s3 = esrc[e+3];
    u16x8 v0 = *(const u16x8*)(X + (size_t)s0*DD + lane*8);
    u16x8 v1 = *(const u16x8*)(X + (size_t)s1*DD + lane*8);
    u16x8 v2 = *(const u16x8*)(X + (size_t)s2*DD + lane*8);
    u16x8 v3 = *(const u16x8*)(X + (size_t)s3*DD + lane*8);
    #pragma unroll
    for (int t = 0; t < 8; t++){
      float f0 = b2f(v0[t]), f1 = b2f(v1[t]), f2 = b2f(v2[t]), f3 = b2f(v3[t]);
      sum[t] += (f0 + f1) + (f2 + f3);
      mx[t] = fmaxf(fmaxf(mx[t], fmaxf(f0, f1)), fmaxf(f2, f3));
    }
  }
  for (; e < end; e++){
    int s = esrc[e];
    u16x8 v = *(const u16x8*)(X + (size_t)s*DD + lane*8);
    #pragma unroll
    for (int t = 0; t < 8; t++){
      float f = b2f(v[t]);
      sum[t] += f;
      mx[t] = fmaxf(mx[t], f);
    }
  }
  if (beg == end){
    #pragma unroll
    for (int t = 0; t < 8; t++) mx[t] = 0.f;
  }
  u16x8 sv, mv;
  #pragma unroll
  for (int t = 0; t < 8; t++){ sv[t] = f2b(sum[t]); mv[t] = f2b(mx[t]); }
  *(u16x8*)(S  + (size_t)node*DD + lane*8) = sv;
  *(u16x8*)(Mx + (size_t)node*DD + lane*8) = mv;
}

// ---------------- GEMM (bf16 MFMA 32x32x16, 128x128 tile, BK=64) -------------
// Round-3 proven skeleton UNCHANGED: stage-all -> syncthreads -> ds_read+MFMA
// -> syncthreads, 32 KiB LDS (multi-block/CU), XOR-swizzled staging (both
// sides), XCD-bijective 1D grid. Only the inner compute shape changed:
// mfma_f32_32x32x16_bf16 (16 MFMA/iter instead of 32, same FLOPs, ~20% less
// matrix-pipe time; same 16 ds_read_b128/iter).
// Layouts (HW-verified, m74/m101): A/B frag: row/col = lane&31, k-half =
// lane>>5 (8 contiguous k each). C/D: col = lane&31, row = (reg&3) +
// 8*(reg>>2) + 4*(lane>>5).
// Swizzle: phys_chunk = logical ^ (row&7) ^ ((row>>3)&3), applied inverse on
// the GLOBAL source (gl_lds writes linearly) and forward on ds_read.
// mode 0: kb: 0=P0(X)@W0, 1=P1(S)@W1, 2=P1(S)@W2 *dscale (epi), 3=P2(Max)@W3
// mode 1: A = concat(P0..P3) along K (K=2048), kb=0
// biases skipped: they cancel in the node-axis normalization
__global__ __launch_bounds__(256) void gemm_stats(
    const unsigned short* __restrict__ P0, const unsigned short* __restrict__ P1,
    const unsigned short* __restrict__ P2, const unsigned short* __restrict__ P3,
    const float* __restrict__ dscale,
    const unsigned short* __restrict__ Wslot,  // [4][DD][K] bf16 ([e][k]) slot base
    int K, int mode,
    unsigned short* __restrict__ Z,            // [4][NN][DD] bf16 (slice = kb)
    float* __restrict__ stats)                 // [4][2][512] slot base
{
  __shared__ __align__(16) unsigned short As[128*64];  // [row][64] phys-swizzled
  __shared__ __align__(16) unsigned short Bs[128*64];

  // ---- bijective XCD swizzle (works for any gridDim) ----
  const int nwg = gridDim.x;
  const int q8 = nwg >> 3, r8 = nwg & 7;
  const int xcd = blockIdx.x & 7, idx8 = blockIdx.x >> 3;
  const int swz = (xcd < r8 ? xcd*(q8+1) : r8*(q8+1) + (xcd-r8)*q8) + idx8;
  int mg, y, kb;
  if (!mode){ mg = swz >> 4; y = (swz >> 2) & 3; kb = swz & 3; }
  else      { mg = swz >> 2; y = swz & 3;        kb = 0; }

  const unsigned short* A = P0;
  int scaleEpi = 0;
  if (!mode){
    if      (kb == 1) A = P1;
    else if (kb == 2){ A = P1; scaleEpi = 1; }
    else if (kb == 3) A = P2;
  }
  const unsigned short* W = Wslot + (size_t)(mode ? 0 : kb) * K * DD;

  const int m0 = mg * 128;
  const int n0 = y * 128;
  const int tid = threadIdx.x;
  const int wid = tid >> 6, lane = tid & 63;
  const int waveM = (wid & 1) * 64, waveN = (wid >> 1) * 64;
  const int l31 = lane & 31, hi = lane >> 5;

  // staging map: call c (0..3) covers rows c*32..c*32+31; thread t -> local
  // row lr = c*32 + sr (sr = t>>3), phys chunk t&7.
  // Global src chunk = (t&7) ^ (lr&7) ^ ((lr>>3)&3) = (t&7) ^ (sr&7) ^ ((sr>>3)&3).
  const int sr = tid >> 3;                         // 0..31
  const int gch = ((tid & 7) ^ (sr & 7) ^ ((sr >> 3) & 3)) * 8;  // elems
  size_t aRow[4], bRow[4];
  #pragma unroll
  for (int c = 0; c < 4; c++){
    int r = m0 + c*32 + sr; if (r > NN-1) r = NN-1;  // clamp; masked in epilogue
    aRow[c] = (size_t)r * DD + gch;
    bRow[c] = (size_t)(n0 + c*32 + sr) * K + gch;
  }

  // fragment reads: row = waveM/N + ti*32 + l31 -> row&7 = l31&7,
  // (row>>3)&3 = (l31>>3)&3 (waveM, ti*32 contribute 0 to both).
  const int rx = (l31 & 7) ^ ((l31 >> 3) & 3);

  const int NT = K >> 6;

  f32x16 acc[2][2];
  #pragma unroll
  for (int i = 0; i < 2; i++)
    #pragma unroll
    for (int j = 0; j < 2; j++)
      #pragma unroll
      for (int r = 0; r < 16; r++) acc[i][j][r] = 0.f;

  for (int t = 0; t < NT; t++){
    const int kt = t << 6;
    const unsigned short* Ak = A;
    int acol = kt;
    if (mode){
      int seg = kt >> 9;
      Ak = (seg == 0) ? P0 : (seg == 1) ? P1 : (seg == 2) ? P2 : P3;
      acol = kt & 511;
    }
    #pragma unroll
    for (int c = 0; c < 4; c++){
      gl_lds16(Ak + aRow[c] + acol, As + c*2048 + tid*8);
      gl_lds16(W + bRow[c] + kt,    Bs + c*2048 + tid*8);
    }
    __syncthreads();
    short8 a[2][4], b[2][4];
    #pragma unroll
    for (int ti = 0; ti < 2; ti++){
      const int ar = (waveM + ti*32 + l31) * 64;
      const int br = (waveN + ti*32 + l31) * 64;
      #pragma unroll
      for (int ks = 0; ks < 4; ks++){
        const int ph = (((ks << 1) | hi) ^ rx) * 8;
        a[ti][ks] = *(const short8*)(As + ar + ph);
        b[ti][ks] = *(const short8*)(Bs + br + ph);
      }
    }
    #pragma unroll
    for (int ks = 0; ks < 4; ks++)
      #pragma unroll
      for (int ti = 0; ti < 2; ti++)
        #pragma unroll
        for (int tj = 0; tj < 2; tj++)
          acc[ti][tj] = __builtin_amdgcn_mfma_f32_32x32x16_bf16(
              a[ti][ks], b[tj][ks], acc[ti][tj], 0, 0, 0);
    __syncthreads();
  }

  // epilogue: optional row-scale (mean branch), store z bf16, column stats
  // C/D: col = l31, row = (reg&3) + 8*(reg>>2) + 4*hi  (within 32x32 tile)
  float dsv[2][16];
  if (scaleEpi){
    #pragma unroll
    for (int ti = 0; ti < 2; ti++)
      #pragma unroll
      for (int reg = 0; reg < 16; reg++){
        int grow = m0 + waveM + ti*32 + (reg & 3) + 8*(reg >> 2) + 4*hi;
        dsv[ti][reg] = dscale[grow < NN ? grow : NN-1];
      }
  }
  #pragma unroll
  for (int tj = 0; tj < 2; tj++){
    float ps = 0.f, pq = 0.f;
    int gcol = n0 + waveN + tj*32 + l31;
    #pragma unroll
    for (int ti = 0; ti < 2; ti++){
      #pragma unroll
      for (int reg = 0; reg < 16; reg++){
        int grow = m0 + waveM + ti*32 + (reg & 3) + 8*(reg >> 2) + 4*hi;
        float v = acc[ti][tj][reg];
        if (scaleEpi) v *= dsv[ti][reg];
        bool ok = grow < NN;
        float vm = ok ? v : 0.f;
        ps += vm; pq += vm*vm;
        if (ok) Z[((size_t)kb*NN + grow)*DD + gcol] = f2b(v);
      }
    }
    ps += __shfl_xor(ps, 32);
    pq += __shfl_xor(pq, 32);
    if (hi == 0){
      atomicAdd(&stats[kb*1024 + gcol], ps);
      atomicAdd(&stats[kb*1024 + 512 + gcol], pq);
    }
  }
}

// ---------------- normalize + relu + weighted combine (4 branches) -----------
__global__ __launch_bounds__(256) void combine_k(
    const unsigned short* __restrict__ Z, const float* __restrict__ stats,
    const float* __restrict__ g, const float* __restrict__ beta,
    const float* __restrict__ w,
    unsigned short* __restrict__ out, int addFlag)
{
  int idx = blockIdx.x*256 + threadIdx.x;
  if (idx >= NN*64) return;
  int node = idx >> 6;
  int e0 = (idx & 63) * 8;
  float acc[8];
  #pragma unroll
  for (int t = 0; t < 8; t++) acc[t] = 0.f;
  const float invn = 1.f / (float)NN;
  #pragma unroll
  for (int k = 0; k < 4; k++){
    float wk = w[k];
    u16x8 zv = *(const u16x8*)(Z + ((size_t)k*NN + node)*DD + e0);
    #pragma unroll
    for (int t = 0; t < 8; t++){
      int e = e0 + t;
      float mu  = stats[k*1024 + e] * invn;
      float var = stats[k*1024 + 512 + e] * invn - mu*mu;
      float inv = rsqrtf(var + EPSF);
      float val = (b2f(zv[t]) - mu) * inv * g[k*DD + e] + beta[k*DD + e];
      acc[t] += wk * fmaxf(val, 0.f);
    }
  }
  unsigned short* op = out + (size_t)node*DD + e0;
  u16x8 res;
  if (addFlag){
    u16x8 prev = *(const u16x8*)op;
    #pragma unroll
    for (int t = 0; t < 8; t++) res[t] = f2b(b2f(prev[t]) + acc[t]);
  } else {
    #pragma unroll
    for (int t = 0; t < 8; t++) res[t] = f2b(acc[t]);
  }
  *(u16x8*)op = res;
}

// ---------------- final BN + relu + residual (reads bf16 h copy) -------------
__global__ __launch_bounds__(256) void bn_k(
    const unsigned short* __restrict__ Z, const float* __restrict__ stats,
    const float* __restrict__ g, const float* __restrict__ b,
    const unsigned short* __restrict__ hb, float* __restrict__ out)
{
  int idx = blockIdx.x*256 + threadIdx.x;
  if (idx >= NN*64) return;
  int node = idx >> 6, e0 = (idx & 63) * 8;
  const float invn = 1.f / (float)NN;
  u16x8 zv = *(const u16x8*)(Z + (size_t)node*DD + e0);
  u16x8 hv = *(const u16x8*)(hb + (size_t)node*DD + e0);
  #pragma unroll
  for (int t = 0; t < 8; t++){
    int e = e0 + t;
    float mu  = stats[e] * invn;
    float var = stats[512 + e] * invn - mu*mu;
    float val = (b2f(zv[t]) - mu) * rsqrtf(var + EPSF) * g[e] + b[e];
    out[(size_t)node*DD + e] = b2f(hv[t]) + fmaxf(val, 0.f);
  }
}

extern "C" void kernel_launch(void* const* d_in, const int* in_sizes, int n_in,
                              void* d_out, int out_size, void* d_ws, size_t ws_size,
                              hipStream_t stream)
{
  const float* h    = (const float*)d_in[0];
  const int*   src  = (const int*)d_in[1];
  const int*   dst  = (const int*)d_in[2];
  const float* wf   = (const float*)d_in[3];
  const float* wm   = (const float*)d_in[4];
  const float* wl   = (const float*)d_in[5];
  const float* pfW  = (const float*)d_in[6];
  const float* pfg  = (const float*)d_in[8];
  const float* pfbt = (const float*)d_in[9];
  const float* pmW  = (const float*)d_in[10];
  const float* pmg  = (const float*)d_in[12];
  const float* pmbt = (const float*)d_in[13];
  const float* plW  = (const float*)d_in[14];
  const float* plg  = (const float*)d_in[16];
  const float* plbt = (const float*)d_in[17];
  const float* catW = (const float*)d_in[18];
  const float* bng  = (const float*)d_in[20];
  const float* bnb  = (const float*)d_in[21];
  float* out = (float*)d_out;
  (void)in_sizes; (void)n_in; (void)out_size;

  // ---- workspace layout (d_ws) ----
  char* ws = (char*)d_ws;
  size_t off = 0;
  auto alloc = [&](size_t bytes)->char*{
    char* p = ws + off;
    off = (off + bytes + 255) & ~(size_t)255;
    return p;
  };
  unsigned short* hb  = (unsigned short*)alloc(STATE_BYTES);   // bf16 h, live to end
  unsigned short* A2  = (unsigned short*)alloc(STATE_BYTES);   // l1
  unsigned short* A3  = (unsigned short*)alloc(STATE_BYTES);   // l2
  int*   esrc   = (int*)alloc((size_t)NE*4);
  int*   cnt    = (int*)alloc((size_t)NN*4);
  int*   cursor = (int*)alloc((size_t)NN*4);
  int*   offs   = (int*)alloc((size_t)(NN+1)*4);
  float* dscale = (float*)alloc((size_t)NN*4);
  float* stats  = (float*)alloc((size_t)11*4096*4);
  unsigned short* Z = (unsigned short*)alloc(4*STATE_BYTES);   // 4 branch slices

  if (off > ws_size){
    probe_k<<<dim3((NN*DD+255)/256), dim3(256), 0, stream>>>(out, (float)ws_size, NN*DD);
    return;
  }

  // ---- buffers hosted outside d_ws ----
  unsigned short* A0 = (unsigned short*)d_out;                         // s1 -> m1
  unsigned short* A1 = (unsigned short*)((char*)d_out + STATE_BYTES);  // s2 -> m2
  unsigned short* Sb = (unsigned short*)h;                             // h dead after cvt
  unsigned short* Mb = (unsigned short*)((char*)h + STATE_BYTES);
  unsigned short* WT_PL  = (unsigned short*)pfW;                       // 10.49 MB in 12.58
  unsigned short* WT_PM  = (unsigned short*)plW;                       // 4.19 MB
  unsigned short* WT_CAT = (unsigned short*)((char*)plW + 4194304);    // 2.10 MB
  unsigned short* WT_PF  = (unsigned short*)((char*)plW + 6291456);    // 6.29 MB (bounced)

  hipMemsetAsync(cnt, 0, (size_t)NN*4, stream);
  hipMemsetAsync(stats, 0, (size_t)11*4096*4, stream);

  // h -> bf16 FIRST (h region becomes scratch afterwards)
  cvt_k<<<dim3(12500), dim3(256), 0, stream>>>(h, hb);

  // CSR
  count_k  <<<dim3((NE+255)/256), dim3(256), 0, stream>>>(dst, cnt);
  scan_k   <<<dim3(1), dim3(1024), 0, stream>>>(cnt, offs, cursor, dscale);
  scatter_k<<<dim3((NE+255)/256), dim3(256), 0, stream>>>(src, dst, cursor, esrc);

  // weight transposes (ordering breaks the src/dst cycle; pf bounces via Z)
  transpose_k<<<dim3(16,16,12), dim3(32,8), 0, stream>>>(pfW, (unsigned short*)Z, 512, 512);
  transpose_k<<<dim3(16,16,20), dim3(32,8), 0, stream>>>(plW, WT_PL, 512, 512);  // kills pfW
  transpose_k<<<dim3(16,16, 8), dim3(32,8), 0, stream>>>(pmW, WT_PM, 512, 512);  // kills plW
  transpose_k<<<dim3(16,64, 1), dim3(32,8), 0, stream>>>(catW, WT_CAT, 2048, 512);
  hipMemcpyAsync(WT_PF, Z, 6291456, hipMemcpyDeviceToDevice, stream);           // Z free now

  dim3 gblock(256);
  dim3 cgrid(12500), cblock(256);

  auto wslot = [&](int slot)->const unsigned short*{
    if (slot < 3)  return WT_PF + (size_t)slot*1048576;
    if (slot < 5)  return WT_PM + (size_t)(slot-3)*1048576;
    return WT_PL + (size_t)(slot-5)*1048576;
  };
  auto agg = [&](const unsigned short* X){
    agg_k<<<dim3(12500), dim3(256), 0, stream>>>(X, offs, esrc, Sb, Mb);
  };
  auto mixed = [&](int slot, const unsigned short* X,
                   const float* wrow, const float* g, const float* beta,
                   unsigned short* o, int add0){
    float* st = stats + (size_t)slot*4096;
    // 1D grid: 391 m-groups x (4 n-blocks x 4 branches) = 6256 blocks
    gemm_stats<<<dim3(391*16), gblock, 0, stream>>>(X, Sb, Mb, Mb, dscale,
        wslot(slot), DD, 0, Z, st);
    combine_k<<<cgrid, cblock, 0, stream>>>(Z, st, g, beta, wrow, o, add0);
  };

  // schedule (slots: 0..2=pf, 3..4=pm, 5..9=pl)
  agg(hb);
  mixed(0, hb, wf,   pfg+0,    pfbt+0,    A0, 0);   // s1
  mixed(1, hb, wf+4, pfg+2048, pfbt+2048, A1, 0);   // s2
  agg(A0);                                          // agg(s1)
  mixed(2, A0, wf+8, pfg+4096, pfbt+4096, A1, 1);   // s2 += f(s1)
  mixed(3, A0, wm,   pmg+0,    pmbt+0,    A0, 0);   // m1 over s1
  agg(A1);                                          // agg(s2)
  mixed(4, A1, wm+4, pmg+2048, pmbt+2048, A1, 0);   // m2 over s2
  agg(A0);                                          // agg(m1)
  mixed(5, A0, wl,    plg+0,    plbt+0,    A2, 0);  // l1
  mixed(7, A0, wl+8,  plg+4096, plbt+4096, A3, 0);  // l2
  agg(A1);                                          // agg(m2)
  mixed(6, A1, wl+4,  plg+2048, plbt+2048, A2, 1);
  mixed(8, A1, wl+12, plg+6144, plbt+6144, A3, 1);
  agg(A2);                                          // agg(l1)
  mixed(9, A2, wl+16, plg+8192, plbt+8192, A3, 1);

  // final: concat(m1,m2,l1,l2) @ cat_W -> BN over nodes -> relu -> + h
  // 1D grid: 391 m-groups x 4 n-blocks = 1564 blocks
  gemm_stats<<<dim3(391*4), gblock, 0, stream>>>(A0, A1, A2, A3, dscale,
      WT_CAT, 4*DD, 1, Z, stats + 10*4096);
  bn_k<<<cgrid, cblock, 0, stream>>>(Z, stats + 10*4096, bng, bnb, hb, out);
}

// Round 6
// 4153.309 us; speedup vs baseline: 2.1605x; 1.1232x over previous
//
#include <hip/hip_runtime.h>
#include <stdint.h>

#define NN 50000
#define NE 800000
#define DD 512
#define EPSF 1e-5f
#define STATE_BYTES ((size_t)NN*DD*2)          // 51,200,000

typedef __attribute__((ext_vector_type(8))) short short8;
typedef __attribute__((ext_vector_type(8))) unsigned short u16x8;
typedef __attribute__((ext_vector_type(4))) float floatx4;

__device__ __forceinline__ unsigned short f2b(float f){
  unsigned int u = __float_as_uint(f);
  u += 0x7fffu + ((u >> 16) & 1u);   // RNE
  return (unsigned short)(u >> 16);
}
__device__ __forceinline__ float b2f(unsigned short b){
  return __uint_as_float(((unsigned int)b) << 16);
}

// async global->LDS, 16B per lane; LDS dest = wave-uniform base + lane*16
__device__ __forceinline__ void gl_lds16(const unsigned short* g, unsigned short* l){
  __builtin_amdgcn_global_load_lds(
      (const __attribute__((address_space(1))) unsigned int*)(uintptr_t)g,
      (__attribute__((address_space(3))) unsigned int*)(uintptr_t)l,
      16, 0, 0);
}

// ---------------- diagnostic probe (fires only if ws too small) ----------------
__global__ void probe_k(float* __restrict__ out, float val, int n){
  int i = blockIdx.x*256 + threadIdx.x;
  if (i < n) out[i] = val;
}

// ---------------- CSR build ----------------
__global__ void count_k(const int* __restrict__ dst, int* __restrict__ cnt){
  int i = blockIdx.x*256 + threadIdx.x;
  if (i < NE) atomicAdd(&cnt[dst[i]], 1);
}

__global__ void scan_k(const int* __restrict__ cnt, int* __restrict__ offs,
                       int* __restrict__ cursor, float* __restrict__ dscale){
  __shared__ int sd[1024];
  __shared__ int run;
  int t = threadIdx.x;
  if (t == 0) run = 0;
  __syncthreads();
  for (int base = 0; base < NN; base += 1024){
    int i = base + t;
    int v = (i < NN) ? cnt[i] : 0;
    sd[t] = v;
    __syncthreads();
    for (int o = 1; o < 1024; o <<= 1){
      int x = (t >= o) ? sd[t-o] : 0;
      __syncthreads();
      sd[t] += x;
      __syncthreads();
    }
    int incl = sd[t];
    int r = run;
    if (i < NN){
      int excl = r + incl - v;
      offs[i] = excl;
      cursor[i] = excl;
      dscale[i] = 1.0f / (float)(v > 0 ? v : 1);
    }
    __syncthreads();
    if (t == 1023) run += incl;
    __syncthreads();
  }
  if (t == 0) offs[NN] = run;
}

__global__ void scatter_k(const int* __restrict__ src, const int* __restrict__ dst,
                          int* __restrict__ cursor, int* __restrict__ esrc){
  int i = blockIdx.x*256 + threadIdx.x;
  if (i < NE){
    int d = dst[i];
    int pos = atomicAdd(&cursor[d], 1);
    esrc[pos] = src[i];
  }
}

// ---------------- h -> bf16 ----------------
__global__ __launch_bounds__(256) void cvt_k(const float* __restrict__ h,
                                             unsigned short* __restrict__ o){
  int idx = blockIdx.x*256 + threadIdx.x;      // NN*64 threads
  if (idx >= NN*64) return;
  const floatx4* hp = (const floatx4*)(h + (size_t)idx*8);
  floatx4 v0 = hp[0], v1 = hp[1];
  u16x8 r;
  #pragma unroll
  for (int t = 0; t < 4; t++){ r[t] = f2b(v0[t]); r[4+t] = f2b(v1[t]); }
  *(u16x8*)(o + (size_t)idx*8) = r;
}

// batched transpose: src [nmat][R][C] f32 -> dst [nmat][C][R] bf16
__global__ void transpose_k(const float* __restrict__ src, unsigned short* __restrict__ dst,
                            int R, int C){
  __shared__ float tile[32][33];
  const float* Sp = src + (size_t)blockIdx.z * R * C;
  unsigned short* Dp = dst + (size_t)blockIdx.z * R * C;
  int c  = blockIdx.x*32 + threadIdx.x;
  int r0 = blockIdx.y*32;
  for (int j = threadIdx.y; j < 32; j += 8)
    tile[j][threadIdx.x] = Sp[(size_t)(r0 + j)*C + c];
  __syncthreads();
  int rr = r0 + threadIdx.x;
  int cc = blockIdx.x*32;
  for (int j = threadIdx.y; j < 32; j += 8)
    Dp[(size_t)(cc + j)*R + rr] = f2b(tile[threadIdx.x][j]);
}

// ---------------- aggregation (one wave per node, 4-edge ILP) ----------------
__global__ __launch_bounds__(256) void agg_k(
    const unsigned short* __restrict__ X,
    const int* __restrict__ offs, const int* __restrict__ esrc,
    unsigned short* __restrict__ S, unsigned short* __restrict__ Mx)
{
  int wave = threadIdx.x >> 6;
  int lane = threadIdx.x & 63;
  int node = blockIdx.x*4 + wave;
  if (node >= NN) return;
  int beg = offs[node], end = offs[node+1];
  float sum[8], mx[8];
  #pragma unroll
  for (int t = 0; t < 8; t++){ sum[t] = 0.f; mx[t] = -3.4e38f; }
  int e = beg;
  for (; e + 4 <= end; e += 4){
    int s0 = esrc[e+0], s1 = esrc[e+1], s2 = esrc[e+2], s3 = esrc[e+3];
    u16x8 v0 = *(const u16x8*)(X + (size_t)s0*DD + lane*8);
    u16x8 v1 = *(const u16x8*)(X + (size_t)s1*DD + lane*8);
    u16x8 v2 = *(const u16x8*)(X + (size_t)s2*DD + lane*8);
    u16x8 v3 = *(const u16x8*)(X + (size_t)s3*DD + lane*8);
    #pragma unroll
    for (int t = 0; t < 8; t++){
      float f0 = b2f(v0[t]), f1 = b2f(v1[t]), f2 = b2f(v2[t]), f3 = b2f(v3[t]);
      sum[t] += (f0 + f1) + (f2 + f3);
      mx[t] = fmaxf(fmaxf(mx[t], fmaxf(f0, f1)), fmaxf(f2, f3));
    }
  }
  for (; e < end; e++){
    int s = esrc[e];
    u16x8 v = *(const u16x8*)(X + (size_t)s*DD + lane*8);
    #pragma unroll
    for (int t = 0; t < 8; t++){
      float f = b2f(v[t]);
      sum[t] += f;
      mx[t] = fmaxf(mx[t], f);
    }
  }
  if (beg == end){
    #pragma unroll
    for (int t = 0; t < 8; t++) mx[t] = 0.f;
  }
  u16x8 sv, mv;
  #pragma unroll
  for (int t = 0; t < 8; t++){ sv[t] = f2b(sum[t]); mv[t] = f2b(mx[t]); }
  *(u16x8*)(S  + (size_t)node*DD + lane*8) = sv;
  *(u16x8*)(Mx + (size_t)node*DD + lane*8) = mv;
}

// ---------------- GEMM (bf16 MFMA 16x16x32, 128x256 tile, BK=64) -------------
// r3 skeleton UNCHANGED (stage-all -> syncthreads -> ds_read+MFMA ->
// syncthreads, single-buffered, both-sides XOR swizzle, XCD-bijective grid).
// r5 proved per-block-iter cost is invariant to compute content -> amortize
// the fixed stage/barrier latency over a 2x wider N-tile: BN=256, block-iters
// halve (50048 -> 25024). A staged once per 256 output cols (A-staging total
// halves). 4 waves, per-wave 64x128 output: acc[4][8] (16x16 frags).
// LDS: A 16KB + B 32KB = 48 KB. __launch_bounds__(256,2) pins regalloc so
// 2 blocks/CU stay resident.
// mode 0: kb: 0=P0(X)@W0, 1=P1(S)@W1, 2=P1(S)@W2 *dscale (epi), 3=P2(Max)@W3
// mode 1: A = concat(P0..P3) along K (K=2048), kb=0
// biases skipped: they cancel in the node-axis normalization
__global__ __launch_bounds__(256, 2) void gemm_stats(
    const unsigned short* __restrict__ P0, const unsigned short* __restrict__ P1,
    const unsigned short* __restrict__ P2, const unsigned short* __restrict__ P3,
    const float* __restrict__ dscale,
    const unsigned short* __restrict__ Wslot,  // [4][DD][K] bf16 ([e][k]) slot base
    int K, int mode,
    unsigned short* __restrict__ Z,            // [4][NN][DD] bf16 (slice = kb)
    float* __restrict__ stats)                 // [4][2][512] slot base
{
  __shared__ __align__(16) unsigned short As[128*64];  // 16 KB, phys-swizzled
  __shared__ __align__(16) unsigned short Bs[256*64];  // 32 KB, phys-swizzled

  // ---- bijective XCD swizzle (works for any gridDim) ----
  const int nwg = gridDim.x;
  const int q8 = nwg >> 3, r8 = nwg & 7;
  const int xcd = blockIdx.x & 7, idx8 = blockIdx.x >> 3;
  const int swz = (xcd < r8 ? xcd*(q8+1) : r8*(q8+1) + (xcd-r8)*q8) + idx8;
  int mg, y, kb;
  if (!mode){ mg = swz >> 3; y = (swz >> 2) & 1; kb = swz & 3; }
  else      { mg = swz >> 1; y = swz & 1;        kb = 0; }

  const unsigned short* A = P0;
  int scaleEpi = 0;
  if (!mode){
    if      (kb == 1) A = P1;
    else if (kb == 2){ A = P1; scaleEpi = 1; }
    else if (kb == 3) A = P2;
  }
  const unsigned short* W = Wslot + (size_t)(mode ? 0 : kb) * K * DD;

  const int m0 = mg * 128;
  const int n0 = y * 256;
  const int tid = threadIdx.x;
  const int wid = tid >> 6, lane = tid & 63;
  const int waveM = (wid & 1) * 64, waveN = (wid >> 1) * 128;
  const int quad = lane >> 4, l15 = lane & 15;

  // staging map: A call c (0..3) covers rows c*32..c*32+31; B call c (0..7).
  // thread t -> local row lr = c*32 + sr (sr = t>>3), phys chunk t&7.
  // Global src chunk = (t&7) ^ (lr&7) = (t&7) ^ (sr&7)  (c*32 ≡ 0 mod 8).
  const int sr = tid >> 3;                         // 0..31
  const int gch = ((tid & 7) ^ (sr & 7)) * 8;      // inverse-swizzled src chunk (elems)
  size_t aRow[4];
  #pragma unroll
  for (int c = 0; c < 4; c++){
    int r = m0 + c*32 + sr; if (r > NN-1) r = NN-1;  // clamp; masked in epilogue
    aRow[c] = (size_t)r * DD + gch;
  }
  const size_t bBase = (size_t)(n0 + sr) * K + gch;  // + c*32*K (uniform)

  // fragment read offsets: row = waveM/N + 16i + l15 (row&7 = l15&7);
  // logical chunk kk*4+quad -> phys ((kk*4+quad)^(l15&7))
  const int rsw = l15 & 7;
  const int ph0 = (quad ^ rsw) * 8;                // kk=0 (elems)
  const int ph1 = ((4 | quad) ^ rsw) * 8;          // kk=1
  const int arow = (waveM + l15) * 64;
  const int brow = (waveN + l15) * 64;

  floatx4 acc[4][8];
  #pragma unroll
  for (int i = 0; i < 4; i++)
    #pragma unroll
    for (int j = 0; j < 8; j++)
      #pragma unroll
      for (int r = 0; r < 4; r++) acc[i][j][r] = 0.f;

  for (int kt = 0; kt < K; kt += 64){
    const unsigned short* Ak = A;
    int acol = kt;
    if (mode){
      int seg = kt >> 9;
      Ak = (seg == 0) ? P0 : (seg == 1) ? P1 : (seg == 2) ? P2 : P3;
      acol = kt & 511;
    }
    // A first (longer-latency stream), then B (L2-hot weights)
    #pragma unroll
    for (int c = 0; c < 4; c++)
      gl_lds16(Ak + aRow[c] + acol, As + c*2048 + tid*8);
    #pragma unroll
    for (int c = 0; c < 8; c++)
      gl_lds16(W + bBase + (size_t)c*32*K + kt, Bs + c*2048 + tid*8);
    __syncthreads();
    short8 a0[4], a1[4], b0[8], b1[8];
    #pragma unroll
    for (int i = 0; i < 4; i++){
      a0[i] = *(const short8*)(As + arow + i*1024 + ph0);
      a1[i] = *(const short8*)(As + arow + i*1024 + ph1);
    }
    #pragma unroll
    for (int j = 0; j < 8; j++){
      b0[j] = *(const short8*)(Bs + brow + j*1024 + ph0);
      b1[j] = *(const short8*)(Bs + brow + j*1024 + ph1);
    }
    #pragma unroll
    for (int i = 0; i < 4; i++)
      #pragma unroll
      for (int j = 0; j < 8; j++){
        acc[i][j] = __builtin_amdgcn_mfma_f32_16x16x32_bf16(a0[i], b0[j], acc[i][j], 0, 0, 0);
        acc[i][j] = __builtin_amdgcn_mfma_f32_16x16x32_bf16(a1[i], b1[j], acc[i][j], 0, 0, 0);
      }
    __syncthreads();
  }

  // epilogue: optional row-scale (mean branch), store z bf16, column stats
  float ds[4][4];
  if (scaleEpi){
    #pragma unroll
    for (int i = 0; i < 4; i++){
      int rbase = m0 + waveM + 16*i + quad*4;
      #pragma unroll
      for (int r = 0; r < 4; r++){
        int grow = rbase + r;
        ds[i][r] = dscale[grow < NN ? grow : NN-1];
      }
    }
  }
  #pragma unroll
  for (int j = 0; j < 8; j++){
    float ps = 0.f, pq = 0.f;
    int gcol = n0 + waveN + 16*j + l15;
    #pragma unroll
    for (int i = 0; i < 4; i++){
      int rbase = m0 + waveM + 16*i + quad*4;
      #pragma unroll
      for (int r = 0; r < 4; r++){
        int grow = rbase + r;
        float v = acc[i][j][r];
        if (scaleEpi) v *= ds[i][r];
        bool ok = grow < NN;
        float vm = ok ? v : 0.f;
        ps += vm; pq += vm*vm;
        if (ok) Z[((size_t)kb*NN + grow)*DD + gcol] = f2b(v);
      }
    }
    ps += __shfl_xor(ps, 16); ps += __shfl_xor(ps, 32);
    pq += __shfl_xor(pq, 16); pq += __shfl_xor(pq, 32);
    if (quad == 0){
      atomicAdd(&stats[kb*1024 + gcol], ps);
      atomicAdd(&stats[kb*1024 + 512 + gcol], pq);
    }
  }
}

// ---------------- normalize + relu + weighted combine (4 branches) -----------
__global__ __launch_bounds__(256) void combine_k(
    const unsigned short* __restrict__ Z, const float* __restrict__ stats,
    const float* __restrict__ g, const float* __restrict__ beta,
    const float* __restrict__ w,
    unsigned short* __restrict__ out, int addFlag)
{
  int idx = blockIdx.x*256 + threadIdx.x;
  if (idx >= NN*64) return;
  int node = idx >> 6;
  int e0 = (idx & 63) * 8;
  float acc[8];
  #pragma unroll
  for (int t = 0; t < 8; t++) acc[t] = 0.f;
  const float invn = 1.f / (float)NN;
  #pragma unroll
  for (int k = 0; k < 4; k++){
    float wk = w[k];
    u16x8 zv = *(const u16x8*)(Z + ((size_t)k*NN + node)*DD + e0);
    #pragma unroll
    for (int t = 0; t < 8; t++){
      int e = e0 + t;
      float mu  = stats[k*1024 + e] * invn;
      float var = stats[k*1024 + 512 + e] * invn - mu*mu;
      float inv = rsqrtf(var + EPSF);
      float val = (b2f(zv[t]) - mu) * inv * g[k*DD + e] + beta[k*DD + e];
      acc[t] += wk * fmaxf(val, 0.f);
    }
  }
  unsigned short* op = out + (size_t)node*DD + e0;
  u16x8 res;
  if (addFlag){
    u16x8 prev = *(const u16x8*)op;
    #pragma unroll
    for (int t = 0; t < 8; t++) res[t] = f2b(b2f(prev[t]) + acc[t]);
  } else {
    #pragma unroll
    for (int t = 0; t < 8; t++) res[t] = f2b(acc[t]);
  }
  *(u16x8*)op = res;
}

// ---------------- final BN + relu + residual (reads bf16 h copy) -------------
__global__ __launch_bounds__(256) void bn_k(
    const unsigned short* __restrict__ Z, const float* __restrict__ stats,
    const float* __restrict__ g, const float* __restrict__ b,
    const unsigned short* __restrict__ hb, float* __restrict__ out)
{
  int idx = blockIdx.x*256 + threadIdx.x;
  if (idx >= NN*64) return;
  int node = idx >> 6, e0 = (idx & 63) * 8;
  const float invn = 1.f / (float)NN;
  u16x8 zv = *(const u16x8*)(Z + (size_t)node*DD + e0);
  u16x8 hv = *(const u16x8*)(hb + (size_t)node*DD + e0);
  #pragma unroll
  for (int t = 0; t < 8; t++){
    int e = e0 + t;
    float mu  = stats[e] * invn;
    float var = stats[512 + e] * invn - mu*mu;
    float val = (b2f(zv[t]) - mu) * rsqrtf(var + EPSF) * g[e] + b[e];
    out[(size_t)node*DD + e] = b2f(hv[t]) + fmaxf(val, 0.f);
  }
}

extern "C" void kernel_launch(void* const* d_in, const int* in_sizes, int n_in,
                              void* d_out, int out_size, void* d_ws, size_t ws_size,
                              hipStream_t stream)
{
  const float* h    = (const float*)d_in[0];
  const int*   src  = (const int*)d_in[1];
  const int*   dst  = (const int*)d_in[2];
  const float* wf   = (const float*)d_in[3];
  const float* wm   = (const float*)d_in[4];
  const float* wl   = (const float*)d_in[5];
  const float* pfW  = (const float*)d_in[6];
  const float* pfg  = (const float*)d_in[8];
  const float* pfbt = (const float*)d_in[9];
  const float* pmW  = (const float*)d_in[10];
  const float* pmg  = (const float*)d_in[12];
  const float* pmbt = (const float*)d_in[13];
  const float* plW  = (const float*)d_in[14];
  const float* plg  = (const float*)d_in[16];
  const float* plbt = (const float*)d_in[17];
  const float* catW = (const float*)d_in[18];
  const float* bng  = (const float*)d_in[20];
  const float* bnb  = (const float*)d_in[21];
  float* out = (float*)d_out;
  (void)in_sizes; (void)n_in; (void)out_size;

  // ---- workspace layout (d_ws) ----
  char* ws = (char*)d_ws;
  size_t off = 0;
  auto alloc = [&](size_t bytes)->char*{
    char* p = ws + off;
    off = (off + bytes + 255) & ~(size_t)255;
    return p;
  };
  unsigned short* hb  = (unsigned short*)alloc(STATE_BYTES);   // bf16 h, live to end
  unsigned short* A2  = (unsigned short*)alloc(STATE_BYTES);   // l1
  unsigned short* A3  = (unsigned short*)alloc(STATE_BYTES);   // l2
  int*   esrc   = (int*)alloc((size_t)NE*4);
  int*   cnt    = (int*)alloc((size_t)NN*4);
  int*   cursor = (int*)alloc((size_t)NN*4);
  int*   offs   = (int*)alloc((size_t)(NN+1)*4);
  float* dscale = (float*)alloc((size_t)NN*4);
  float* stats  = (float*)alloc((size_t)11*4096*4);
  unsigned short* Z = (unsigned short*)alloc(4*STATE_BYTES);   // 4 branch slices

  if (off > ws_size){
    probe_k<<<dim3((NN*DD+255)/256), dim3(256), 0, stream>>>(out, (float)ws_size, NN*DD);
    return;
  }

  // ---- buffers hosted outside d_ws ----
  unsigned short* A0 = (unsigned short*)d_out;                         // s1 -> m1
  unsigned short* A1 = (unsigned short*)((char*)d_out + STATE_BYTES);  // s2 -> m2
  unsigned short* Sb = (unsigned short*)h;                             // h dead after cvt
  unsigned short* Mb = (unsigned short*)((char*)h + STATE_BYTES);
  unsigned short* WT_PL  = (unsigned short*)pfW;                       // 10.49 MB in 12.58
  unsigned short* WT_PM  = (unsigned short*)plW;                       // 4.19 MB
  unsigned short* WT_CAT = (unsigned short*)((char*)plW + 4194304);    // 2.10 MB
  unsigned short* WT_PF  = (unsigned short*)((char*)plW + 6291456);    // 6.29 MB (bounced)

  hipMemsetAsync(cnt, 0, (size_t)NN*4, stream);
  hipMemsetAsync(stats, 0, (size_t)11*4096*4, stream);

  // h -> bf16 FIRST (h region becomes scratch afterwards)
  cvt_k<<<dim3(12500), dim3(256), 0, stream>>>(h, hb);

  // CSR
  count_k  <<<dim3((NE+255)/256), dim3(256), 0, stream>>>(dst, cnt);
  scan_k   <<<dim3(1), dim3(1024), 0, stream>>>(cnt, offs, cursor, dscale);
  scatter_k<<<dim3((NE+255)/256), dim3(256), 0, stream>>>(src, dst, cursor, esrc);

  // weight transposes (ordering breaks the src/dst cycle; pf bounces via Z)
  transpose_k<<<dim3(16,16,12), dim3(32,8), 0, stream>>>(pfW, (unsigned short*)Z, 512, 512);
  transpose_k<<<dim3(16,16,20), dim3(32,8), 0, stream>>>(plW, WT_PL, 512, 512);  // kills pfW
  transpose_k<<<dim3(16,16, 8), dim3(32,8), 0, stream>>>(pmW, WT_PM, 512, 512);  // kills plW
  transpose_k<<<dim3(16,64, 1), dim3(32,8), 0, stream>>>(catW, WT_CAT, 2048, 512);
  hipMemcpyAsync(WT_PF, Z, 6291456, hipMemcpyDeviceToDevice, stream);           // Z free now

  dim3 gblock(256);
  dim3 cgrid(12500), cblock(256);

  auto wslot = [&](int slot)->const unsigned short*{
    if (slot < 3)  return WT_PF + (size_t)slot*1048576;
    if (slot < 5)  return WT_PM + (size_t)(slot-3)*1048576;
    return WT_PL + (size_t)(slot-5)*1048576;
  };
  auto agg = [&](const unsigned short* X){
    agg_k<<<dim3(12500), dim3(256), 0, stream>>>(X, offs, esrc, Sb, Mb);
  };
  auto mixed = [&](int slot, const unsigned short* X,
                   const float* wrow, const float* g, const float* beta,
                   unsigned short* o, int add0){
    float* st = stats + (size_t)slot*4096;
    // 1D grid: 391 m-groups x (2 n-blocks x 4 branches) = 3128 blocks
    gemm_stats<<<dim3(391*8), gblock, 0, stream>>>(X, Sb, Mb, Mb, dscale,
        wslot(slot), DD, 0, Z, st);
    combine_k<<<cgrid, cblock, 0, stream>>>(Z, st, g, beta, wrow, o, add0);
  };

  // schedule (slots: 0..2=pf, 3..4=pm, 5..9=pl)
  agg(hb);
  mixed(0, hb, wf,   pfg+0,    pfbt+0,    A0, 0);   // s1
  mixed(1, hb, wf+4, pfg+2048, pfbt+2048, A1, 0);   // s2
  agg(A0);                                          // agg(s1)
  mixed(2, A0, wf+8, pfg+4096, pfbt+4096, A1, 1);   // s2 += f(s1)
  mixed(3, A0, wm,   pmg+0,    pmbt+0,    A0, 0);   // m1 over s1
  agg(A1);                                          // agg(s2)
  mixed(4, A1, wm+4, pmg+2048, pmbt+2048, A1, 0);   // m2 over s2
  agg(A0);                                          // agg(m1)
  mixed(5, A0, wl,    plg+0,    plbt+0,    A2, 0);  // l1
  mixed(7, A0, wl+8,  plg+4096, plbt+4096, A3, 0);  // l2
  agg(A1);                                          // agg(m2)
  mixed(6, A1, wl+4,  plg+2048, plbt+2048, A2, 1);
  mixed(8, A1, wl+12, plg+6144, plbt+6144, A3, 1);
  agg(A2);                                          // agg(l1)
  mixed(9, A2, wl+16, plg+8192, plbt+8192, A3, 1);

  // final: concat(m1,m2,l1,l2) @ cat_W -> BN over nodes -> relu -> + h
  // 1D grid: 391 m-groups x 2 n-blocks = 782 blocks
  gemm_stats<<<dim3(391*2), gblock, 0, stream>>>(A0, A1, A2, A3, dscale,
      WT_CAT, 4*DD, 1, Z, stats + 10*4096);
  bn_k<<<cgrid, cblock, 0, stream>>>(Z, stats + 10*4096, bng, bnb, hb, out);
}